// Round 1
// baseline (2225.666 us; speedup 1.0000x reference)
//
#include <hip/hip_runtime.h>
#include <math.h>

#define N_NODES 50000
#define N_EDGES 800000
#define IN_C 96
#define HID_C 64
#define OUT_C 40
#define ALPHA 0.2f
#define NEG_SLOPE 0.01f

// ---------------- edge-index dtype handling ----------------
// edge_index is jnp.int64 in the reference; depending on jax x64 config the
// harness may hand us int32 or int64. Detect on device: for int64 (little
// endian) the high 32-bit words of small node ids are all zero.
__global__ void detect_i64_k(const unsigned int* ei, int* flag) {
    int is64 = 1;
    for (int i = 1; i < 16; i += 2)
        if (ei[i] != 0u) is64 = 0;
    *flag = is64;
}

__device__ __forceinline__ int edge_at(const void* ei, int is64, long long pos) {
    return is64 ? (int)((const long long*)ei)[pos] : ((const int*)ei)[pos];
}

// ---------------- degree / norm ----------------
__global__ void fill_ones_k(float* p, int n) {
    int i = blockIdx.x * blockDim.x + threadIdx.x;
    if (i < n) p[i] = 1.0f;  // self-loop contributes 1 to every node's degree
}

__global__ void deg_scatter_k(const void* ei, const int* flag, float* deg, int E) {
    int e = blockIdx.x * blockDim.x + threadIdx.x;
    if (e < E) {
        int d = edge_at(ei, *flag, (long long)E + e);  // edge_index[1][e]
        atomicAdd(&deg[d], 1.0f);
    }
}

__global__ void rsqrt_k(float* p, int n) {
    int i = blockIdx.x * blockDim.x + threadIdx.x;
    if (i < n) p[i] = rsqrtf(p[i]);  // deg >= 1 always (self loop)
}

// ---------------- propagation ----------------
// out[i] = dinv[i]^2 * in[i]  (self-loop edge, src==dst)
template <int C>
__global__ void selfloop_k(const float* __restrict__ in, const float* __restrict__ dinv,
                           float* __restrict__ out, int n) {
    int i = blockIdx.x * blockDim.x + threadIdx.x;
    if (i < n * C) {
        int node = i / C;
        float d = dinv[node];
        out[i] = d * d * in[i];
    }
}

// one thread per (edge, channel): out[dst,c] += dinv[s]*dinv[d]*in[src,c]
template <int C>
__global__ void edge_scatter_k(const void* ei, const int* flag,
                               const float* __restrict__ dinv,
                               const float* __restrict__ in,
                               float* __restrict__ out, int E) {
    long long i = (long long)blockIdx.x * blockDim.x + threadIdx.x;
    if (i >= (long long)E * C) return;
    int e = (int)(i / C);
    int c = (int)(i - (long long)e * C);
    int f = *flag;
    int s = edge_at(ei, f, e);
    int d = edge_at(ei, f, (long long)E + e);
    float w = dinv[s] * dinv[d];
    atomicAdd(&out[(long long)d * C + c], w * in[(long long)s * C + c]);
}

// ---------------- dense linear (no bias): out[n,o] = sum_k in[n,k] * W[o,k] ----------------
template <int O>
__global__ void lin_k(const float* __restrict__ in, const float* __restrict__ W,
                      float* __restrict__ out, int N, int K) {
    extern __shared__ float Wl[];  // W transposed: Wl[k*O + o]
    for (int j = threadIdx.x; j < K * O; j += blockDim.x) {
        int o = j / K, k = j - o * K;
        Wl[k * O + o] = W[j];
    }
    __syncthreads();
    int idx = blockIdx.x * blockDim.x + threadIdx.x;
    if (idx >= N * O) return;
    int n = idx / O, o = idx - n * O;
    const float* row = in + (long long)n * K;
    float s = 0.0f;
    for (int k = 0; k < K; ++k) s += row[k] * Wl[k * O + o];
    out[idx] = s;
}

// ---------------- elementwise ----------------
template <int C>
__global__ void bias_add_k(const float* __restrict__ in, const float* __restrict__ b,
                           float* __restrict__ out, int n) {
    int i = blockIdx.x * blockDim.x + threadIdx.x;
    if (i < n * C) out[i] = in[i] + b[i % C];
}

// out = a*P + b*H, optionally leaky_relu
__global__ void combine_k(const float* __restrict__ P, const float* __restrict__ H,
                          float* __restrict__ out, int n, float a, float b, int leaky) {
    int i = blockIdx.x * blockDim.x + threadIdx.x;
    if (i < n) {
        float v = a * P[i] + b * H[i];
        if (leaky) v = v > 0.0f ? v : NEG_SLOPE * v;
        out[i] = v;
    }
}

// ---------------- bias + log_softmax over 40 channels, one wave per node ----------------
__global__ void softmax40_k(const float* __restrict__ in, const float* __restrict__ bias,
                            float* __restrict__ out, int N) {
    int gtid = blockIdx.x * blockDim.x + threadIdx.x;
    int node = gtid >> 6;
    int lane = gtid & 63;
    if (node >= N) return;
    float v = -INFINITY;
    if (lane < OUT_C) v = in[node * OUT_C + lane] + bias[lane];
    float m = v;
    #pragma unroll
    for (int off = 32; off >= 1; off >>= 1) m = fmaxf(m, __shfl_xor(m, off));
    float e = (lane < OUT_C) ? expf(v - m) : 0.0f;
    float s = e;
    #pragma unroll
    for (int off = 32; off >= 1; off >>= 1) s += __shfl_xor(s, off);
    float ls = logf(s);
    if (lane < OUT_C) out[node * OUT_C + lane] = (v - m) - ls;
}

// ---------------- launcher ----------------
static inline int cdiv(long long a, long long b) { return (int)((a + b - 1) / b); }

extern "C" void kernel_launch(void* const* d_in, const int* in_sizes, int n_in,
                              void* d_out, int out_size, void* d_ws, size_t ws_size,
                              hipStream_t stream) {
    const float* x  = (const float*)d_in[0];
    const void*  ei = d_in[1];
    const float* W0 = (const float*)d_in[2];
    const float* b0 = (const float*)d_in[3];
    const float* W4 = (const float*)d_in[4];
    const float* b4 = (const float*)d_in[5];
    float* out = (float*)d_out;

    const int N = N_NODES, E = N_EDGES;
    float* ws   = (float*)d_ws;
    int*   flag = (int*)d_ws;                 // 1 int; reserve 64 floats
    float* dinv = ws + 64;                    // N   (used as deg first)
    float* bufA = dinv + N;                   // N*64 (also reused as N*40)
    float* bufB = bufA + (long long)N * HID_C;
    float* bufC = bufB + (long long)N * HID_C;

    const int T = 256;

    detect_i64_k<<<1, 1, 0, stream>>>((const unsigned int*)ei, flag);

    // degree + dinv (in place in dinv)
    fill_ones_k<<<cdiv(N, T), T, 0, stream>>>(dinv, N);
    deg_scatter_k<<<cdiv(E, T), T, 0, stream>>>(ei, flag, dinv, E);
    rsqrt_k<<<cdiv(N, T), T, 0, stream>>>(dinv, N);

    // ---- conv0 (SGConv, K=2): fold linear first: bufA = x @ W0^T ----
    lin_k<HID_C><<<cdiv((long long)N * HID_C, T), T, IN_C * HID_C * 4, stream>>>(x, W0, bufA, N, IN_C);
    // prop twice at 64ch: A->B, B->A
    selfloop_k<HID_C><<<cdiv((long long)N * HID_C, T), T, 0, stream>>>(bufA, dinv, bufB, N);
    edge_scatter_k<HID_C><<<cdiv((long long)E * HID_C, T), T, 0, stream>>>(ei, flag, dinv, bufA, bufB, E);
    selfloop_k<HID_C><<<cdiv((long long)N * HID_C, T), T, 0, stream>>>(bufB, dinv, bufA, N);
    edge_scatter_k<HID_C><<<cdiv((long long)E * HID_C, T), T, 0, stream>>>(ei, flag, dinv, bufB, bufA, E);
    // + b0 -> bufC (= h0 for APPNP)
    bias_add_k<HID_C><<<cdiv((long long)N * HID_C, T), T, 0, stream>>>(bufA, b0, bufC, N);

    // ---- conv1..conv3: leaky_relu(APPNP(h)) at 64ch, h0 lives in bufC ----
    for (int r = 0; r < 3; ++r) {
        // z1 = (1-a)*prop(h0) + a*h0   -> bufB
        selfloop_k<HID_C><<<cdiv((long long)N * HID_C, T), T, 0, stream>>>(bufC, dinv, bufA, N);
        edge_scatter_k<HID_C><<<cdiv((long long)E * HID_C, T), T, 0, stream>>>(ei, flag, dinv, bufC, bufA, E);
        combine_k<<<cdiv((long long)N * HID_C, T), T, 0, stream>>>(bufA, bufC, bufB, N * HID_C,
                                                                   1.0f - ALPHA, ALPHA, 0);
        // h = leaky((1-a)*prop(z1) + a*h0) -> bufC (elementwise, safe in place)
        selfloop_k<HID_C><<<cdiv((long long)N * HID_C, T), T, 0, stream>>>(bufB, dinv, bufA, N);
        edge_scatter_k<HID_C><<<cdiv((long long)E * HID_C, T), T, 0, stream>>>(ei, flag, dinv, bufB, bufA, E);
        combine_k<<<cdiv((long long)N * HID_C, T), T, 0, stream>>>(bufA, bufC, bufC, N * HID_C,
                                                                   1.0f - ALPHA, ALPHA, 1);
    }

    // ---- conv4 (SGConv, K=2): fold linear first, 40ch props (reuse bufA/bufB) ----
    lin_k<OUT_C><<<cdiv((long long)N * OUT_C, T), T, HID_C * OUT_C * 4, stream>>>(bufC, W4, bufA, N, HID_C);
    selfloop_k<OUT_C><<<cdiv((long long)N * OUT_C, T), T, 0, stream>>>(bufA, dinv, bufB, N);
    edge_scatter_k<OUT_C><<<cdiv((long long)E * OUT_C, T), T, 0, stream>>>(ei, flag, dinv, bufA, bufB, E);
    selfloop_k<OUT_C><<<cdiv((long long)N * OUT_C, T), T, 0, stream>>>(bufB, dinv, bufA, N);
    edge_scatter_k<OUT_C><<<cdiv((long long)E * OUT_C, T), T, 0, stream>>>(ei, flag, dinv, bufB, bufA, E);

    // ---- + b4, log_softmax ----
    softmax40_k<<<cdiv((long long)N * 64, T), T, 0, stream>>>(bufA, b4, out, N);
}

// Round 2
// 982.985 us; speedup vs baseline: 2.2642x; 2.2642x over previous
//
#include <hip/hip_runtime.h>
#include <math.h>

#define N_NODES 50000
#define N_EDGES 800000
#define IN_C 96
#define HID_C 64
#define OUT_C 40
#define ALPHA 0.2f
#define NEG_SLOPE 0.01f

// ---------------- edge-index dtype handling ----------------
// edge_index is jnp.int64 in the reference; depending on jax x64 config the
// harness may hand us int32 or int64. Detect on device: for int64 (little
// endian) the high 32-bit words of small node ids are all zero.
__global__ void detect_i64_k(const unsigned int* ei, int* flag) {
    int is64 = 1;
    for (int i = 1; i < 16; i += 2)
        if (ei[i] != 0u) is64 = 0;
    *flag = is64;
}

__device__ __forceinline__ int edge_at(const void* ei, int is64, long long pos) {
    return is64 ? (int)((const long long*)ei)[pos] : ((const int*)ei)[pos];
}

// ---------------- CSR build ----------------
__global__ void zero_int_k(int* p, int n) {
    int i = blockIdx.x * blockDim.x + threadIdx.x;
    if (i < n) p[i] = 0;
}

__global__ void deg_hist_k(const void* ei, const int* flag, int* deg, int E) {
    int e = blockIdx.x * blockDim.x + threadIdx.x;
    if (e < E) {
        int d = edge_at(ei, *flag, (long long)E + e);
        atomicAdd(&deg[d], 1);
    }
}

// single-block exclusive scan over deg[n] -> rowptr[n+1], cursor[n]
__global__ void __launch_bounds__(1024) scan_k(const int* __restrict__ deg,
                                               int* __restrict__ rowptr,
                                               int* __restrict__ cursor, int n) {
    __shared__ int part[1024];
    int t = threadIdx.x;
    int chunk = (n + 1023) / 1024;
    int lo = t * chunk;
    int hi = lo + chunk; if (hi > n) hi = n;
    int s = 0;
    for (int i = lo; i < hi; ++i) s += deg[i];
    part[t] = s;
    __syncthreads();
    for (int off = 1; off < 1024; off <<= 1) {
        int v = (t >= off) ? part[t - off] : 0;
        __syncthreads();
        part[t] += v;
        __syncthreads();
    }
    int base = (t == 0) ? 0 : part[t - 1];  // exclusive prefix of this chunk
    for (int i = lo; i < hi; ++i) {
        rowptr[i] = base;
        cursor[i] = base;
        base += deg[i];
    }
    if (t == 1023) rowptr[n] = part[1023];
}

__global__ void dinv_k(const int* __restrict__ deg, float* __restrict__ dinv, int n) {
    int i = blockIdx.x * blockDim.x + threadIdx.x;
    if (i < n) dinv[i] = rsqrtf((float)deg[i] + 1.0f);  // +1 self loop
}

// fill CSR: for each edge, place (src, w) into dst's segment
__global__ void csr_fill_k(const void* ei, const int* flag,
                           const float* __restrict__ dinv,
                           int* __restrict__ cursor,
                           int* __restrict__ csrc, float* __restrict__ cw, int E) {
    int e = blockIdx.x * blockDim.x + threadIdx.x;
    if (e >= E) return;
    int f = *flag;
    int s = edge_at(ei, f, e);
    int d = edge_at(ei, f, (long long)E + e);
    int pos = atomicAdd(&cursor[d], 1);
    csrc[pos] = s;
    cw[pos] = dinv[s] * dinv[d];
}

// ---------------- fused propagation (gather, no atomics) ----------------
// out[d] = selfloop + sum_{incoming e} w_e * in[src_e]
// COMBINE: out = (1-ALPHA)*prop + ALPHA*h0 ; LEAKY: leaky_relu epilogue
template <int C, bool COMBINE, bool LEAKY>
__global__ void prop_k(const int* __restrict__ rowptr, const int* __restrict__ csrc,
                       const float* __restrict__ cw, const float* __restrict__ dinv,
                       const float* __restrict__ in, const float* __restrict__ h0,
                       float* __restrict__ out, int N) {
    int node = blockIdx.x * (blockDim.x >> 6) + (threadIdx.x >> 6);
    int lane = threadIdx.x & 63;
    if (node >= N) return;
    float di = dinv[node];
    float acc = 0.0f;
    if (lane < C) acc = di * di * in[(long long)node * C + lane];  // self loop
    int r0 = rowptr[node], r1 = rowptr[node + 1];
    int i = r0;
    for (; i + 1 < r1; i += 2) {  // 2-way unroll for outstanding loads
        int s0 = csrc[i], s1 = csrc[i + 1];
        float w0 = cw[i], w1 = cw[i + 1];
        float v0 = 0.0f, v1 = 0.0f;
        if (lane < C) {
            v0 = in[(long long)s0 * C + lane];
            v1 = in[(long long)s1 * C + lane];
        }
        acc += w0 * v0 + w1 * v1;
    }
    if (i < r1) {
        int s0 = csrc[i];
        float w0 = cw[i];
        if (lane < C) acc += w0 * in[(long long)s0 * C + lane];
    }
    if (lane < C) {
        float v = acc;
        if (COMBINE) v = (1.0f - ALPHA) * acc + ALPHA * h0[(long long)node * C + lane];
        if (LEAKY) v = v > 0.0f ? v : NEG_SLOPE * v;
        out[(long long)node * C + lane] = v;
    }
}

// ---------------- dense linear (no bias): out[n,o] = sum_k in[n,k] * W[o,k] ----------------
template <int O>
__global__ void lin_k(const float* __restrict__ in, const float* __restrict__ W,
                      float* __restrict__ out, int N, int K) {
    extern __shared__ float Wl[];  // W transposed: Wl[k*O + o]
    for (int j = threadIdx.x; j < K * O; j += blockDim.x) {
        int o = j / K, k = j - o * K;
        Wl[k * O + o] = W[j];
    }
    __syncthreads();
    int idx = blockIdx.x * blockDim.x + threadIdx.x;
    if (idx >= N * O) return;
    int n = idx / O, o = idx - n * O;
    const float* row = in + (long long)n * K;
    float s = 0.0f;
    for (int k = 0; k < K; ++k) s += row[k] * Wl[k * O + o];
    out[idx] = s;
}

template <int C>
__global__ void bias_add_k(const float* __restrict__ in, const float* __restrict__ b,
                           float* __restrict__ out, int n) {
    int i = blockIdx.x * blockDim.x + threadIdx.x;
    if (i < n * C) out[i] = in[i] + b[i % C];
}

// ---------------- bias + log_softmax over 40 channels, one wave per node ----------------
__global__ void softmax40_k(const float* __restrict__ in, const float* __restrict__ bias,
                            float* __restrict__ out, int N) {
    int gtid = blockIdx.x * blockDim.x + threadIdx.x;
    int node = gtid >> 6;
    int lane = gtid & 63;
    if (node >= N) return;
    float v = -INFINITY;
    if (lane < OUT_C) v = in[node * OUT_C + lane] + bias[lane];
    float m = v;
    #pragma unroll
    for (int off = 32; off >= 1; off >>= 1) m = fmaxf(m, __shfl_xor(m, off));
    float e = (lane < OUT_C) ? expf(v - m) : 0.0f;
    float s = e;
    #pragma unroll
    for (int off = 32; off >= 1; off >>= 1) s += __shfl_xor(s, off);
    float ls = logf(s);
    if (lane < OUT_C) out[node * OUT_C + lane] = (v - m) - ls;
}

// ---------------- launcher ----------------
static inline int cdiv(long long a, long long b) { return (int)((a + b - 1) / b); }

extern "C" void kernel_launch(void* const* d_in, const int* in_sizes, int n_in,
                              void* d_out, int out_size, void* d_ws, size_t ws_size,
                              hipStream_t stream) {
    const float* x  = (const float*)d_in[0];
    const void*  ei = d_in[1];
    const float* W0 = (const float*)d_in[2];
    const float* b0 = (const float*)d_in[3];
    const float* W4 = (const float*)d_in[4];
    const float* b4 = (const float*)d_in[5];
    float* out = (float*)d_out;

    const int N = N_NODES, E = N_EDGES;
    char* ws = (char*)d_ws;
    int*   flag   = (int*)ws;                          ws += 256;
    int*   deg    = (int*)ws;                          ws += (size_t)N * 4;
    int*   rowptr = (int*)ws;                          ws += (size_t)(N + 1) * 4;
    int*   cursor = (int*)ws;                          ws += (size_t)N * 4;
    float* dinv   = (float*)ws;                        ws += (size_t)N * 4;
    int*   csrc   = (int*)ws;                          ws += (size_t)E * 4;
    float* cw     = (float*)ws;                        ws += (size_t)E * 4;
    float* bufA   = (float*)ws;                        ws += (size_t)N * HID_C * 4;
    float* bufB   = (float*)ws;                        ws += (size_t)N * HID_C * 4;
    float* bufC   = (float*)ws;                        ws += (size_t)N * HID_C * 4;

    const int T = 256;
    const int NPB = T / 64;  // nodes per block in prop_k

    detect_i64_k<<<1, 1, 0, stream>>>((const unsigned int*)ei, flag);

    // ---- CSR build ----
    zero_int_k<<<cdiv(N, T), T, 0, stream>>>(deg, N);
    deg_hist_k<<<cdiv(E, T), T, 0, stream>>>(ei, flag, deg, E);
    scan_k<<<1, 1024, 0, stream>>>(deg, rowptr, cursor, N);
    dinv_k<<<cdiv(N, T), T, 0, stream>>>(deg, dinv, N);
    csr_fill_k<<<cdiv(E, T), T, 0, stream>>>(ei, flag, dinv, cursor, csrc, cw, E);

    // ---- conv0 (SGConv, K=2): linear folded before props (commutes) ----
    lin_k<HID_C><<<cdiv((long long)N * HID_C, T), T, IN_C * HID_C * 4, stream>>>(x, W0, bufA, N, IN_C);
    prop_k<HID_C, false, false><<<cdiv(N, NPB), T, 0, stream>>>(rowptr, csrc, cw, dinv, bufA, nullptr, bufB, N);
    prop_k<HID_C, false, false><<<cdiv(N, NPB), T, 0, stream>>>(rowptr, csrc, cw, dinv, bufB, nullptr, bufA, N);
    bias_add_k<HID_C><<<cdiv((long long)N * HID_C, T), T, 0, stream>>>(bufA, b0, bufC, N);

    // ---- conv1..conv3: leaky_relu(APPNP(h)), h0 = bufC ----
    for (int r = 0; r < 3; ++r) {
        prop_k<HID_C, true, false><<<cdiv(N, NPB), T, 0, stream>>>(rowptr, csrc, cw, dinv, bufC, bufC, bufB, N);
        // in-place write to bufC is safe: h0[node] is read only by the thread that writes it
        prop_k<HID_C, true, true><<<cdiv(N, NPB), T, 0, stream>>>(rowptr, csrc, cw, dinv, bufB, bufC, bufC, N);
    }

    // ---- conv4 (SGConv, K=2): linear folded first, props at 40ch ----
    lin_k<OUT_C><<<cdiv((long long)N * OUT_C, T), T, HID_C * OUT_C * 4, stream>>>(bufC, W4, bufA, N, HID_C);
    prop_k<OUT_C, false, false><<<cdiv(N, NPB), T, 0, stream>>>(rowptr, csrc, cw, dinv, bufA, nullptr, bufB, N);
    prop_k<OUT_C, false, false><<<cdiv(N, NPB), T, 0, stream>>>(rowptr, csrc, cw, dinv, bufB, nullptr, bufA, N);

    // ---- + b4, log_softmax ----
    softmax40_k<<<cdiv((long long)N * 64, T), T, 0, stream>>>(bufA, b4, out, N);
}

// Round 3
// 676.043 us; speedup vs baseline: 3.2922x; 1.4540x over previous
//
#include <hip/hip_runtime.h>
#include <hip/hip_fp16.h>
#include <math.h>

#define N_NODES 50000
#define N_EDGES 800000
#define IN_C 96
#define HID_C 64
#define OUT_C 40
#define ALPHA 0.2f
#define NEG_SLOPE 0.01f

// ---------------- edge-index dtype handling ----------------
__global__ void detect_i64_k(const unsigned int* ei, int* flag) {
    int is64 = 1;
    for (int i = 1; i < 16; i += 2)
        if (ei[i] != 0u) is64 = 0;
    *flag = is64;
}

__device__ __forceinline__ int edge_at(const void* ei, int is64, long long pos) {
    return is64 ? (int)((const long long*)ei)[pos] : ((const int*)ei)[pos];
}

// ---------------- CSR build ----------------
__global__ void zero_int_k(int* p, int n) {
    int i = blockIdx.x * blockDim.x + threadIdx.x;
    if (i < n) p[i] = 0;
}

__global__ void deg_hist_k(const void* ei, const int* flag, int* deg, int E) {
    int e = blockIdx.x * blockDim.x + threadIdx.x;
    if (e < E) {
        int d = edge_at(ei, *flag, (long long)E + e);
        atomicAdd(&deg[d], 1);
    }
}

__global__ void __launch_bounds__(1024) scan_k(const int* __restrict__ deg,
                                               int* __restrict__ rowptr,
                                               int* __restrict__ cursor, int n) {
    __shared__ int part[1024];
    int t = threadIdx.x;
    int chunk = (n + 1023) / 1024;
    int lo = t * chunk;
    int hi = lo + chunk; if (hi > n) hi = n;
    int s = 0;
    for (int i = lo; i < hi; ++i) s += deg[i];
    part[t] = s;
    __syncthreads();
    for (int off = 1; off < 1024; off <<= 1) {
        int v = (t >= off) ? part[t - off] : 0;
        __syncthreads();
        part[t] += v;
        __syncthreads();
    }
    int base = (t == 0) ? 0 : part[t - 1];
    for (int i = lo; i < hi; ++i) {
        rowptr[i] = base;
        cursor[i] = base;
        base += deg[i];
    }
    if (t == 1023) rowptr[n] = part[1023];
}

__global__ void dinv_k(const int* __restrict__ deg, float* __restrict__ dinv, int n) {
    int i = blockIdx.x * blockDim.x + threadIdx.x;
    if (i < n) dinv[i] = rsqrtf((float)deg[i] + 1.0f);  // +1 self loop
}

__global__ void csr_fill_k(const void* ei, const int* flag,
                           const float* __restrict__ dinv,
                           int* __restrict__ cursor,
                           int* __restrict__ csrc, float* __restrict__ cw, int E) {
    int e = blockIdx.x * blockDim.x + threadIdx.x;
    if (e >= E) return;
    int f = *flag;
    int s = edge_at(ei, f, e);
    int d = edge_at(ei, f, (long long)E + e);
    int pos = atomicAdd(&cursor[d], 1);
    csrc[pos] = s;
    cw[pos] = dinv[s] * dinv[d];
}

// ---------------- fused propagation (gather, fp16 storage, fp32 math) ----------------
// One wave per node. Lanes split into two 32-lane halves; each half walks
// alternate incoming edges, each lane covers 2 channels via half2 (4 B/lane ->
// 128 B per gathered row at C=64). Partial sums combined via shfl_xor(32).
template <int C, bool COMBINE, bool LEAKY, bool BIAS>
__global__ void prop16_k(const int* __restrict__ rowptr, const int* __restrict__ csrc,
                         const float* __restrict__ cw, const float* __restrict__ dinv,
                         const __half* __restrict__ in, const __half* __restrict__ h0,
                         const float* __restrict__ bias,
                         __half* __restrict__ out, int N) {
    constexpr int CP = C / 2;  // half2 elements per row (32 or 20)
    int node = blockIdx.x * (blockDim.x >> 6) + (threadIdx.x >> 6);
    int lane = threadIdx.x & 63;
    int sub = lane >> 5;
    int ci = lane & 31;
    if (node >= N) return;
    bool act = ci < CP;
    const __half2* in2 = (const __half2*)in;
    float2 acc = make_float2(0.0f, 0.0f);
    float di = dinv[node];
    if (sub == 0 && act) {  // self loop
        float2 v = __half22float2(in2[(long long)node * CP + ci]);
        acc.x = di * di * v.x;
        acc.y = di * di * v.y;
    }
    int r0 = rowptr[node], r1 = rowptr[node + 1];
    int i = r0 + sub;
    for (; i + 2 < r1; i += 4) {  // 2-deep unroll within this half-wave
        int s0 = csrc[i], s1 = csrc[i + 2];
        float w0 = cw[i], w1 = cw[i + 2];
        float2 v0 = make_float2(0.f, 0.f), v1 = make_float2(0.f, 0.f);
        if (act) {
            v0 = __half22float2(in2[(long long)s0 * CP + ci]);
            v1 = __half22float2(in2[(long long)s1 * CP + ci]);
        }
        acc.x += w0 * v0.x + w1 * v1.x;
        acc.y += w0 * v0.y + w1 * v1.y;
    }
    if (i < r1) {
        int s0 = csrc[i];
        float w0 = cw[i];
        if (act) {
            float2 v0 = __half22float2(in2[(long long)s0 * CP + ci]);
            acc.x += w0 * v0.x;
            acc.y += w0 * v0.y;
        }
    }
    // combine the two half-wave partials
    acc.x += __shfl_xor(acc.x, 32);
    acc.y += __shfl_xor(acc.y, 32);
    if (sub == 0 && act) {
        float2 v = acc;
        if (BIAS) { v.x += bias[2 * ci]; v.y += bias[2 * ci + 1]; }
        if (COMBINE) {
            float2 h = __half22float2(((const __half2*)h0)[(long long)node * CP + ci]);
            v.x = (1.0f - ALPHA) * acc.x + ALPHA * h.x;
            v.y = (1.0f - ALPHA) * acc.y + ALPHA * h.y;
        }
        if (LEAKY) {
            v.x = v.x > 0.0f ? v.x : NEG_SLOPE * v.x;
            v.y = v.y > 0.0f ? v.y : NEG_SLOPE * v.y;
        }
        ((__half2*)out)[(long long)node * CP + ci] = __float22half2_rn(v);
    }
}

// ---------------- tiled dense linear: out[n,o] = sum_k in[n,k]*W[o,k], fp16 out ----
// 64-node block tile; thread computes 4 nodes x 4 outputs from LDS-staged
// operands. +2-float row padding -> conflict-free staging writes AND reads.
template <int O, int K, typename InT>
__global__ void lin16_k(const InT* __restrict__ in, const float* __restrict__ W,
                        __half* __restrict__ out, int N) {
    constexpr int TN = 64;
    constexpr int XS = TN + 2;  // 66
    constexpr int WSR = O + 2;
    extern __shared__ float lds[];
    float* xs = lds;             // [K][XS]  transposed input tile
    float* ws = lds + K * XS;    // [K][WSR] transposed weights
    int n0 = blockIdx.x * TN;
    int tid = threadIdx.x;
    int B = blockDim.x;
    for (int idx = tid; idx < TN * K; idx += B) {
        int n = idx / K, k = idx - n * K;  // consecutive threads -> consecutive k: coalesced
        float v = 0.0f;
        if (n0 + n < N) v = (float)in[(long long)(n0 + n) * K + k];
        xs[k * XS + n] = v;  // write stride XS=66 -> bank delta 2 -> free
    }
    for (int idx = tid; idx < O * K; idx += B) {
        int o = idx / K, k = idx - o * K;
        ws[k * WSR + o] = W[idx];
    }
    __syncthreads();
    int nt = tid & 15;
    int ot = tid >> 4;
    if (ot >= O / 4) return;
    float acc[4][4];
    #pragma unroll
    for (int a = 0; a < 4; ++a)
        #pragma unroll
        for (int b = 0; b < 4; ++b) acc[a][b] = 0.0f;
    for (int k = 0; k < K; ++k) {
        const float2* xa = (const float2*)&xs[k * XS + nt * 4];
        const float2* wb = (const float2*)&ws[k * WSR + ot * 4];
        float2 a01 = xa[0], a23 = xa[1];
        float2 b01 = wb[0], b23 = wb[1];
        float a[4] = {a01.x, a01.y, a23.x, a23.y};
        float b[4] = {b01.x, b01.y, b23.x, b23.y};
        #pragma unroll
        for (int ii = 0; ii < 4; ++ii)
            #pragma unroll
            for (int jj = 0; jj < 4; ++jj) acc[ii][jj] += a[ii] * b[jj];
    }
    #pragma unroll
    for (int ii = 0; ii < 4; ++ii) {
        int n = n0 + nt * 4 + ii;
        if (n < N) {
            #pragma unroll
            for (int jj = 0; jj < 4; ++jj)
                out[(long long)n * O + ot * 4 + jj] = __float2half(acc[ii][jj]);
        }
    }
}

// ---------------- bias + log_softmax over 40 channels, one wave per node ----------------
__global__ void softmax40_k(const __half* __restrict__ in, const float* __restrict__ bias,
                            float* __restrict__ out, int N) {
    int gtid = blockIdx.x * blockDim.x + threadIdx.x;
    int node = gtid >> 6;
    int lane = gtid & 63;
    if (node >= N) return;
    float v = -INFINITY;
    if (lane < OUT_C) v = __half2float(in[(long long)node * OUT_C + lane]) + bias[lane];
    float m = v;
    #pragma unroll
    for (int off = 32; off >= 1; off >>= 1) m = fmaxf(m, __shfl_xor(m, off));
    float e = (lane < OUT_C) ? expf(v - m) : 0.0f;
    float s = e;
    #pragma unroll
    for (int off = 32; off >= 1; off >>= 1) s += __shfl_xor(s, off);
    float ls = logf(s);
    if (lane < OUT_C) out[(long long)node * OUT_C + lane] = (v - m) - ls;
}

// ---------------- launcher ----------------
static inline int cdiv(long long a, long long b) { return (int)((a + b - 1) / b); }
static inline size_t align256(size_t x) { return (x + 255) & ~(size_t)255; }

extern "C" void kernel_launch(void* const* d_in, const int* in_sizes, int n_in,
                              void* d_out, int out_size, void* d_ws, size_t ws_size,
                              hipStream_t stream) {
    const float* x  = (const float*)d_in[0];
    const void*  ei = d_in[1];
    const float* W0 = (const float*)d_in[2];
    const float* b0 = (const float*)d_in[3];
    const float* W4 = (const float*)d_in[4];
    const float* b4 = (const float*)d_in[5];
    float* out = (float*)d_out;

    const int N = N_NODES, E = N_EDGES;
    char* ws = (char*)d_ws;
    int*    flag   = (int*)ws;     ws += 256;
    int*    deg    = (int*)ws;     ws += align256((size_t)N * 4);
    int*    rowptr = (int*)ws;     ws += align256((size_t)(N + 1) * 4);
    int*    cursor = (int*)ws;     ws += align256((size_t)N * 4);
    float*  dinv   = (float*)ws;   ws += align256((size_t)N * 4);
    int*    csrc   = (int*)ws;     ws += align256((size_t)E * 4);
    float*  cw     = (float*)ws;   ws += align256((size_t)E * 4);
    __half* bufA   = (__half*)ws;  ws += align256((size_t)N * HID_C * 2);
    __half* bufB   = (__half*)ws;  ws += align256((size_t)N * HID_C * 2);
    __half* bufC   = (__half*)ws;  ws += align256((size_t)N * HID_C * 2);

    const int T = 256;
    const int NPB = T / 64;  // nodes per block in prop16_k

    detect_i64_k<<<1, 1, 0, stream>>>((const unsigned int*)ei, flag);

    // ---- CSR build ----
    zero_int_k<<<cdiv(N, T), T, 0, stream>>>(deg, N);
    deg_hist_k<<<cdiv(E, T), T, 0, stream>>>(ei, flag, deg, E);
    scan_k<<<1, 1024, 0, stream>>>(deg, rowptr, cursor, N);
    dinv_k<<<cdiv(N, T), T, 0, stream>>>(deg, dinv, N);
    csr_fill_k<<<cdiv(E, T), T, 0, stream>>>(ei, flag, dinv, cursor, csrc, cw, E);

    // ---- conv0 (SGConv, K=2): linear folded before props (commutes) ----
    lin16_k<HID_C, IN_C, float><<<cdiv(N, 64), 256,
        (IN_C * 66 + IN_C * (HID_C + 2)) * 4, stream>>>(x, W0, bufA, N);
    prop16_k<HID_C, false, false, false><<<cdiv(N, NPB), T, 0, stream>>>(
        rowptr, csrc, cw, dinv, bufA, nullptr, nullptr, bufB, N);
    prop16_k<HID_C, false, false, true><<<cdiv(N, NPB), T, 0, stream>>>(
        rowptr, csrc, cw, dinv, bufB, nullptr, b0, bufC, N);  // + b0 fused -> h0

    // ---- conv1..conv3: leaky_relu(APPNP(h)), h0 = bufC ----
    for (int r = 0; r < 3; ++r) {
        prop16_k<HID_C, true, false, false><<<cdiv(N, NPB), T, 0, stream>>>(
            rowptr, csrc, cw, dinv, bufC, bufC, nullptr, bufB, N);
        // in-place bufC write safe: h0[node] read only by the wave writing it
        prop16_k<HID_C, true, true, false><<<cdiv(N, NPB), T, 0, stream>>>(
            rowptr, csrc, cw, dinv, bufB, bufC, nullptr, bufC, N);
    }

    // ---- conv4 (SGConv, K=2): linear folded first, props at 40ch ----
    lin16_k<OUT_C, HID_C, __half><<<cdiv(N, 64), 192,
        (HID_C * 66 + HID_C * (OUT_C + 2)) * 4, stream>>>(bufC, W4, bufA, N);
    prop16_k<OUT_C, false, false, false><<<cdiv(N, NPB), T, 0, stream>>>(
        rowptr, csrc, cw, dinv, bufA, nullptr, nullptr, bufB, N);
    prop16_k<OUT_C, false, false, false><<<cdiv(N, NPB), T, 0, stream>>>(
        rowptr, csrc, cw, dinv, bufB, nullptr, nullptr, bufA, N);

    // ---- + b4, log_softmax ----
    softmax40_k<<<cdiv((long long)N * 64, T), T, 0, stream>>>(bufA, b4, out, N);
}

// Round 4
// 538.616 us; speedup vs baseline: 4.1322x; 1.2551x over previous
//
#include <hip/hip_runtime.h>
#include <hip/hip_fp16.h>
#include <math.h>

#define N_NODES 50000
#define N_EDGES 800000
#define IN_C 96
#define HID_C 64
#define OUT_C 40
#define ALPHA 0.2f
#define NEG_SLOPE 0.01f

// ---------------- edge-index dtype handling ----------------
__global__ void detect_i64_k(const unsigned int* ei, int* flag) {
    int is64 = 1;
    for (int i = 1; i < 16; i += 2)
        if (ei[i] != 0u) is64 = 0;
    *flag = is64;
}

__device__ __forceinline__ int edge_at(const void* ei, int is64, long long pos) {
    return is64 ? (int)((const long long*)ei)[pos] : ((const int*)ei)[pos];
}

// ---------------- CSR build ----------------
__global__ void zero_int_k(int* p, int n) {
    int i = blockIdx.x * blockDim.x + threadIdx.x;
    if (i < n) p[i] = 0;
}

__global__ void deg_hist_k(const void* ei, const int* flag, int* deg, int E) {
    int e = blockIdx.x * blockDim.x + threadIdx.x;
    if (e < E) {
        int d = edge_at(ei, *flag, (long long)E + e);
        atomicAdd(&deg[d], 1);
    }
}

// ---- parallel 3-phase exclusive scan over deg[n] ----
// phase 1: per-block totals
__global__ void scan_p1_k(const int* __restrict__ deg, int* __restrict__ part, int n) {
    __shared__ int sm[256];
    int t = threadIdx.x, i = blockIdx.x * 256 + t;
    int v = (i < n) ? deg[i] : 0;
    sm[t] = v;
    __syncthreads();
    for (int off = 1; off < 256; off <<= 1) {
        int u = (t >= off) ? sm[t - off] : 0;
        __syncthreads();
        sm[t] += u;
        __syncthreads();
    }
    if (t == 255) part[blockIdx.x] = sm[255];
}

// phase 2: single-block scan of <=256 partials -> exclusive offsets in place
__global__ void scan_p2_k(int* part, int nb, int* rowptr, int n) {
    __shared__ int sm[256];
    int t = threadIdx.x;
    int v = (t < nb) ? part[t] : 0;
    sm[t] = v;
    __syncthreads();
    for (int off = 1; off < 256; off <<= 1) {
        int u = (t >= off) ? sm[t - off] : 0;
        __syncthreads();
        sm[t] += u;
        __syncthreads();
    }
    if (t < nb) part[t] = sm[t] - v;  // exclusive
    if (t == 255) rowptr[n] = sm[255];
}

// phase 3: rescan + write rowptr/cursor; dinv fused
__global__ void scan_p3_k(const int* __restrict__ deg, const int* __restrict__ part,
                          int* __restrict__ rowptr, int* __restrict__ cursor,
                          float* __restrict__ dinv, int n) {
    __shared__ int sm[256];
    int t = threadIdx.x, i = blockIdx.x * 256 + t;
    int v = (i < n) ? deg[i] : 0;
    sm[t] = v;
    __syncthreads();
    for (int off = 1; off < 256; off <<= 1) {
        int u = (t >= off) ? sm[t - off] : 0;
        __syncthreads();
        sm[t] += u;
        __syncthreads();
    }
    if (i < n) {
        int excl = sm[t] - v + part[blockIdx.x];
        rowptr[i] = excl;
        cursor[i] = excl;
        dinv[i] = rsqrtf((float)v + 1.0f);  // +1 self loop
    }
}

// fill CSR: packed 8B record (src, w) per edge -> one scattered store
__global__ void csr_fill_k(const void* ei, const int* flag,
                           const float* __restrict__ dinv,
                           int* __restrict__ cursor, int2* __restrict__ erec, int E) {
    int e = blockIdx.x * blockDim.x + threadIdx.x;
    if (e >= E) return;
    int f = *flag;
    int s = edge_at(ei, f, e);
    int d = edge_at(ei, f, (long long)E + e);
    int pos = atomicAdd(&cursor[d], 1);
    float w = dinv[s] * dinv[d];
    erec[pos] = make_int2(s, __float_as_int(w));
}

// ---------------- fused propagation (gather, fp16 storage, fp32 math) ----------------
// One wave per node; two 32-lane halves walk alternate incoming edges, 4-deep
// unrolled (8 row-gathers in flight per wave). Lane covers 2 channels (half2).
template <int C, bool COMBINE, bool LEAKY, bool BIAS>
__global__ void prop16_k(const int* __restrict__ rowptr, const int2* __restrict__ erec,
                         const float* __restrict__ dinv,
                         const __half* __restrict__ in, const __half* __restrict__ h0,
                         const float* __restrict__ bias,
                         __half* __restrict__ out, int N) {
    constexpr int CP = C / 2;  // half2 per row (32 or 20)
    int node = blockIdx.x * (blockDim.x >> 6) + (threadIdx.x >> 6);
    int lane = threadIdx.x & 63;
    int sub = lane >> 5;
    int ci = lane & 31;
    if (node >= N) return;
    bool act = ci < CP;
    const __half2* in2 = (const __half2*)in;
    float2 acc = make_float2(0.0f, 0.0f);
    float di = dinv[node];
    if (sub == 0 && act) {  // self loop
        float2 v = __half22float2(in2[(long long)node * CP + ci]);
        acc.x = di * di * v.x;
        acc.y = di * di * v.y;
    }
    int r0 = rowptr[node], r1 = rowptr[node + 1];
    int i = r0 + sub;
    for (; i + 6 < r1; i += 8) {
        int2 e0 = erec[i], e1 = erec[i + 2], e2 = erec[i + 4], e3 = erec[i + 6];
        float2 v0 = make_float2(0.f, 0.f), v1 = v0, v2 = v0, v3 = v0;
        if (act) {
            v0 = __half22float2(in2[(long long)e0.x * CP + ci]);
            v1 = __half22float2(in2[(long long)e1.x * CP + ci]);
            v2 = __half22float2(in2[(long long)e2.x * CP + ci]);
            v3 = __half22float2(in2[(long long)e3.x * CP + ci]);
        }
        float w0 = __int_as_float(e0.y), w1 = __int_as_float(e1.y);
        float w2 = __int_as_float(e2.y), w3 = __int_as_float(e3.y);
        acc.x += w0 * v0.x + w1 * v1.x + w2 * v2.x + w3 * v3.x;
        acc.y += w0 * v0.y + w1 * v1.y + w2 * v2.y + w3 * v3.y;
    }
    for (; i < r1; i += 2) {
        int2 e0 = erec[i];
        if (act) {
            float w0 = __int_as_float(e0.y);
            float2 v0 = __half22float2(in2[(long long)e0.x * CP + ci]);
            acc.x += w0 * v0.x;
            acc.y += w0 * v0.y;
        }
    }
    acc.x += __shfl_xor(acc.x, 32);
    acc.y += __shfl_xor(acc.y, 32);
    if (sub == 0 && act) {
        float2 v = acc;
        if (BIAS) { v.x += bias[2 * ci]; v.y += bias[2 * ci + 1]; }
        if (COMBINE) {
            float2 h = __half22float2(((const __half2*)h0)[(long long)node * CP + ci]);
            v.x = (1.0f - ALPHA) * acc.x + ALPHA * h.x;
            v.y = (1.0f - ALPHA) * acc.y + ALPHA * h.y;
        }
        if (LEAKY) {
            v.x = v.x > 0.0f ? v.x : NEG_SLOPE * v.x;
            v.y = v.y > 0.0f ? v.y : NEG_SLOPE * v.y;
        }
        ((__half2*)out)[(long long)node * CP + ci] = __float22half2_rn(v);
    }
}

// ---------------- tiled dense linear: out[n,o] = sum_k in[n,k]*W[o,k], fp16 out ----
template <int O, int K, typename InT>
__global__ void lin16_k(const InT* __restrict__ in, const float* __restrict__ W,
                        __half* __restrict__ out, int N) {
    constexpr int TN = 64;
    constexpr int XS = TN + 2;  // 66
    constexpr int WSR = O + 2;
    extern __shared__ float lds[];
    float* xs = lds;             // [K][XS]  transposed input tile
    float* ws = lds + K * XS;    // [K][WSR] transposed weights
    int n0 = blockIdx.x * TN;
    int tid = threadIdx.x;
    int B = blockDim.x;
    for (int idx = tid; idx < TN * K; idx += B) {
        int n = idx / K, k = idx - n * K;
        float v = 0.0f;
        if (n0 + n < N) v = (float)in[(long long)(n0 + n) * K + k];
        xs[k * XS + n] = v;
    }
    for (int idx = tid; idx < O * K; idx += B) {
        int o = idx / K, k = idx - o * K;
        ws[k * WSR + o] = W[idx];
    }
    __syncthreads();
    int nt = tid & 15;
    int ot = tid >> 4;
    if (ot >= O / 4) return;
    float acc[4][4];
    #pragma unroll
    for (int a = 0; a < 4; ++a)
        #pragma unroll
        for (int b = 0; b < 4; ++b) acc[a][b] = 0.0f;
    for (int k = 0; k < K; ++k) {
        const float2* xa = (const float2*)&xs[k * XS + nt * 4];
        const float2* wb = (const float2*)&ws[k * WSR + ot * 4];
        float2 a01 = xa[0], a23 = xa[1];
        float2 b01 = wb[0], b23 = wb[1];
        float a[4] = {a01.x, a01.y, a23.x, a23.y};
        float b[4] = {b01.x, b01.y, b23.x, b23.y};
        #pragma unroll
        for (int ii = 0; ii < 4; ++ii)
            #pragma unroll
            for (int jj = 0; jj < 4; ++jj) acc[ii][jj] += a[ii] * b[jj];
    }
    #pragma unroll
    for (int ii = 0; ii < 4; ++ii) {
        int n = n0 + nt * 4 + ii;
        if (n < N) {
            #pragma unroll
            for (int jj = 0; jj < 4; ++jj)
                out[(long long)n * O + ot * 4 + jj] = __float2half(acc[ii][jj]);
        }
    }
}

// ---------------- bias + log_softmax over 40 channels, one wave per node ----------------
__global__ void softmax40_k(const __half* __restrict__ in, const float* __restrict__ bias,
                            float* __restrict__ out, int N) {
    int gtid = blockIdx.x * blockDim.x + threadIdx.x;
    int node = gtid >> 6;
    int lane = gtid & 63;
    if (node >= N) return;
    float v = -INFINITY;
    if (lane < OUT_C) v = __half2float(in[(long long)node * OUT_C + lane]) + bias[lane];
    float m = v;
    #pragma unroll
    for (int off = 32; off >= 1; off >>= 1) m = fmaxf(m, __shfl_xor(m, off));
    float e = (lane < OUT_C) ? expf(v - m) : 0.0f;
    float s = e;
    #pragma unroll
    for (int off = 32; off >= 1; off >>= 1) s += __shfl_xor(s, off);
    float ls = logf(s);
    if (lane < OUT_C) out[(long long)node * OUT_C + lane] = (v - m) - ls;
}

// ---------------- launcher ----------------
static inline int cdiv(long long a, long long b) { return (int)((a + b - 1) / b); }
static inline size_t align256(size_t x) { return (x + 255) & ~(size_t)255; }

extern "C" void kernel_launch(void* const* d_in, const int* in_sizes, int n_in,
                              void* d_out, int out_size, void* d_ws, size_t ws_size,
                              hipStream_t stream) {
    const float* x  = (const float*)d_in[0];
    const void*  ei = d_in[1];
    const float* W0 = (const float*)d_in[2];
    const float* b0 = (const float*)d_in[3];
    const float* W4 = (const float*)d_in[4];
    const float* b4 = (const float*)d_in[5];
    float* out = (float*)d_out;

    const int N = N_NODES, E = N_EDGES;
    const int NB = cdiv(N, 256);  // 196 scan blocks (<=256 required)
    char* ws = (char*)d_ws;
    int*    flag   = (int*)ws;     ws += 256;
    int*    deg    = (int*)ws;     ws += align256((size_t)N * 4);
    int*    rowptr = (int*)ws;     ws += align256((size_t)(N + 1) * 4);
    int*    cursor = (int*)ws;     ws += align256((size_t)N * 4);
    int*    part   = (int*)ws;     ws += align256(256 * 4);
    float*  dinv   = (float*)ws;   ws += align256((size_t)N * 4);
    int2*   erec   = (int2*)ws;    ws += align256((size_t)E * 8);
    __half* bufA   = (__half*)ws;  ws += align256((size_t)N * HID_C * 2);
    __half* bufB   = (__half*)ws;  ws += align256((size_t)N * HID_C * 2);
    __half* bufC   = (__half*)ws;  ws += align256((size_t)N * HID_C * 2);

    const int T = 256;
    const int NPB = T / 64;  // nodes per block in prop16_k

    detect_i64_k<<<1, 1, 0, stream>>>((const unsigned int*)ei, flag);

    // ---- CSR build ----
    zero_int_k<<<cdiv(N, T), T, 0, stream>>>(deg, N);
    deg_hist_k<<<cdiv(E, T), T, 0, stream>>>(ei, flag, deg, E);
    scan_p1_k<<<NB, 256, 0, stream>>>(deg, part, N);
    scan_p2_k<<<1, 256, 0, stream>>>(part, NB, rowptr, N);
    scan_p3_k<<<NB, 256, 0, stream>>>(deg, part, rowptr, cursor, dinv, N);
    csr_fill_k<<<cdiv(E, T), T, 0, stream>>>(ei, flag, dinv, cursor, erec, E);

    // ---- conv0 (SGConv, K=2): linear folded before props (commutes) ----
    lin16_k<HID_C, IN_C, float><<<cdiv(N, 64), 256,
        (IN_C * 66 + IN_C * (HID_C + 2)) * 4, stream>>>(x, W0, bufA, N);
    prop16_k<HID_C, false, false, false><<<cdiv(N, NPB), T, 0, stream>>>(
        rowptr, erec, dinv, bufA, nullptr, nullptr, bufB, N);
    prop16_k<HID_C, false, false, true><<<cdiv(N, NPB), T, 0, stream>>>(
        rowptr, erec, dinv, bufB, nullptr, b0, bufC, N);  // + b0 fused -> h0

    // ---- conv1..conv3: leaky_relu(APPNP(h)), h0 = bufC ----
    for (int r = 0; r < 3; ++r) {
        prop16_k<HID_C, true, false, false><<<cdiv(N, NPB), T, 0, stream>>>(
            rowptr, erec, dinv, bufC, bufC, nullptr, bufB, N);
        prop16_k<HID_C, true, true, false><<<cdiv(N, NPB), T, 0, stream>>>(
            rowptr, erec, dinv, bufB, bufC, nullptr, bufC, N);
    }

    // ---- conv4 (SGConv, K=2): linear folded first, props at 40ch ----
    lin16_k<OUT_C, HID_C, __half><<<cdiv(N, 64), 192,
        (HID_C * 66 + HID_C * (OUT_C + 2)) * 4, stream>>>(bufC, W4, bufA, N);
    prop16_k<OUT_C, false, false, false><<<cdiv(N, NPB), T, 0, stream>>>(
        rowptr, erec, dinv, bufA, nullptr, nullptr, bufB, N);
    prop16_k<OUT_C, false, false, false><<<cdiv(N, NPB), T, 0, stream>>>(
        rowptr, erec, dinv, bufB, nullptr, nullptr, bufA, N);

    // ---- + b4, log_softmax ----
    softmax40_k<<<cdiv((long long)N * 64, T), T, 0, stream>>>(bufA, b4, out, N);
}

// Round 5
// 498.382 us; speedup vs baseline: 4.4658x; 1.0807x over previous
//
#include <hip/hip_runtime.h>
#include <hip/hip_fp16.h>
#include <math.h>

#define N_NODES 50000
#define N_EDGES 800000
#define IN_C 96
#define HID_C 64
#define OUT_C 40
#define ALPHA 0.2f
#define NEG_SLOPE 0.01f

typedef _Float16 f16x8 __attribute__((ext_vector_type(8)));
typedef float f32x4 __attribute__((ext_vector_type(4)));

// ---------------- edge-index dtype handling ----------------
__global__ void detect_i64_k(const unsigned int* ei, int* flag) {
    int is64 = 1;
    for (int i = 1; i < 16; i += 2)
        if (ei[i] != 0u) is64 = 0;
    *flag = is64;
}

__device__ __forceinline__ int edge_at(const void* ei, int is64, long long pos) {
    return is64 ? (int)((const long long*)ei)[pos] : ((const int*)ei)[pos];
}

// ---------------- CSR build ----------------
__global__ void zero_int_k(int* p, int n) {
    int i = blockIdx.x * blockDim.x + threadIdx.x;
    if (i < n) p[i] = 0;
}

__global__ void deg_hist_k(const void* ei, const int* flag, int* deg, int E) {
    int e = blockIdx.x * blockDim.x + threadIdx.x;
    if (e < E) {
        int d = edge_at(ei, *flag, (long long)E + e);
        atomicAdd(&deg[d], 1);
    }
}

// ---- parallel 3-phase exclusive scan over deg[n] ----
__global__ void scan_p1_k(const int* __restrict__ deg, int* __restrict__ part, int n) {
    __shared__ int sm[256];
    int t = threadIdx.x, i = blockIdx.x * 256 + t;
    int v = (i < n) ? deg[i] : 0;
    sm[t] = v;
    __syncthreads();
    for (int off = 1; off < 256; off <<= 1) {
        int u = (t >= off) ? sm[t - off] : 0;
        __syncthreads();
        sm[t] += u;
        __syncthreads();
    }
    if (t == 255) part[blockIdx.x] = sm[255];
}

__global__ void scan_p2_k(int* part, int nb, int* rowptr, int n) {
    __shared__ int sm[256];
    int t = threadIdx.x;
    int v = (t < nb) ? part[t] : 0;
    sm[t] = v;
    __syncthreads();
    for (int off = 1; off < 256; off <<= 1) {
        int u = (t >= off) ? sm[t - off] : 0;
        __syncthreads();
        sm[t] += u;
        __syncthreads();
    }
    if (t < nb) part[t] = sm[t] - v;  // exclusive
    if (t == 255) rowptr[n] = sm[255];
}

__global__ void scan_p3_k(const int* __restrict__ deg, const int* __restrict__ part,
                          int* __restrict__ rowptr, int* __restrict__ cursor,
                          float* __restrict__ dinv, int n) {
    __shared__ int sm[256];
    int t = threadIdx.x, i = blockIdx.x * 256 + t;
    int v = (i < n) ? deg[i] : 0;
    sm[t] = v;
    __syncthreads();
    for (int off = 1; off < 256; off <<= 1) {
        int u = (t >= off) ? sm[t - off] : 0;
        __syncthreads();
        sm[t] += u;
        __syncthreads();
    }
    if (i < n) {
        int excl = sm[t] - v + part[blockIdx.x];
        rowptr[i] = excl;
        cursor[i] = excl;
        dinv[i] = rsqrtf((float)v + 1.0f);  // +1 self loop
    }
}

// fill CSR: src only (4 B/edge) — weights folded into G-space storage
__global__ void csr_fill_k(const void* ei, const int* flag,
                           int* __restrict__ cursor, int* __restrict__ csrc, int E) {
    int e = blockIdx.x * blockDim.x + threadIdx.x;
    if (e >= E) return;
    int f = *flag;
    int s = edge_at(ei, f, e);
    int d = edge_at(ei, f, (long long)E + e);
    int pos = atomicAdd(&cursor[d], 1);
    csrc[pos] = s;
}

// ---------------- fused propagation in G-space (G = dinv * h) ----------------
// S = sum_{incoming} G[src] + G[node];  epilogue:
//   v = dinv^SPOW * S; if BIAS v += dinv*b; if COMBINE v = 0.8v + 0.2*Gh0; leaky.
// One wave per node; two 32-lane halves walk alternate edges, 4-deep unrolled.
template <int C, int SPOW, bool COMBINE, bool LEAKY, bool BIAS>
__global__ void prop16_k(const int* __restrict__ rowptr, const int* __restrict__ csrc,
                         const float* __restrict__ dinv,
                         const __half* __restrict__ in, const __half* __restrict__ h0,
                         const float* __restrict__ bias,
                         __half* __restrict__ out, int N) {
    constexpr int CP = C / 2;  // half2 per row (32 or 20)
    int node = blockIdx.x * (blockDim.x >> 6) + (threadIdx.x >> 6);
    int lane = threadIdx.x & 63;
    int sub = lane >> 5;
    int ci = lane & 31;
    if (node >= N) return;
    bool act = ci < CP;
    const __half2* in2 = (const __half2*)in;
    float2 acc = make_float2(0.0f, 0.0f);
    if (sub == 0 && act) {  // self-loop term G[node]
        float2 v = __half22float2(in2[(long long)node * CP + ci]);
        acc.x = v.x;
        acc.y = v.y;
    }
    int r0 = rowptr[node], r1 = rowptr[node + 1];
    int i = r0 + sub;
    for (; i + 6 < r1; i += 8) {
        int s0 = csrc[i], s1 = csrc[i + 2], s2 = csrc[i + 4], s3 = csrc[i + 6];
        if (act) {
            float2 v0 = __half22float2(in2[(long long)s0 * CP + ci]);
            float2 v1 = __half22float2(in2[(long long)s1 * CP + ci]);
            float2 v2 = __half22float2(in2[(long long)s2 * CP + ci]);
            float2 v3 = __half22float2(in2[(long long)s3 * CP + ci]);
            acc.x += (v0.x + v1.x) + (v2.x + v3.x);
            acc.y += (v0.y + v1.y) + (v2.y + v3.y);
        }
    }
    for (; i < r1; i += 2) {
        int s0 = csrc[i];
        if (act) {
            float2 v0 = __half22float2(in2[(long long)s0 * CP + ci]);
            acc.x += v0.x;
            acc.y += v0.y;
        }
    }
    acc.x += __shfl_xor(acc.x, 32);
    acc.y += __shfl_xor(acc.y, 32);
    if (sub == 0 && act) {
        float di = dinv[node];
        float sc = (SPOW == 2) ? di * di : di;
        float2 v;
        v.x = sc * acc.x;
        v.y = sc * acc.y;
        if (BIAS) { v.x += di * bias[2 * ci]; v.y += di * bias[2 * ci + 1]; }
        if (COMBINE) {
            float2 h = __half22float2(((const __half2*)h0)[(long long)node * CP + ci]);
            v.x = (1.0f - ALPHA) * v.x + ALPHA * h.x;
            v.y = (1.0f - ALPHA) * v.y + ALPHA * h.y;
        }
        if (LEAKY) {  // valid in G-space: dinv > 0 (positive homogeneity)
            v.x = v.x > 0.0f ? v.x : NEG_SLOPE * v.x;
            v.y = v.y > 0.0f ? v.y : NEG_SLOPE * v.y;
        }
        ((__half2*)out)[(long long)node * CP + ci] = __float22half2_rn(v);
    }
}

// ---------------- MFMA dense linear: out[m,o] = sum_k in[m,k]*W[o,k] -------------
// One wave per 16-node tile (M = 50000 = 3125 x 16 exactly). W staged in LDS as
// fp16, row pitch 104 halves: rows 16B-aligned, b128 reads worst-case 2-way bank
// aliased (free). A-frag: lane holds A[m=lane&15][k=quad*8+j] -> coalesced 128B
// row segments. C/D: col=lane&15, row=quad*4+reg. SCALE multiplies rows by
// dinv[m] (h-space -> G-space); G-space input needs no scale (row scaling
// commutes with right-matmul).
template <int O, int K, bool FP32IN, bool SCALE>
__global__ void __launch_bounds__(256) mfma_lin_k(const void* __restrict__ in_,
                                                  const float* __restrict__ W,
                                                  const float* __restrict__ dinv,
                                                  __half* __restrict__ out, int Mtiles) {
    constexpr int P2 = 52;  // half2 pitch (= 104 halves = 208 B rows)
    __shared__ __half2 wsh[O * P2];
    for (int idx = threadIdx.x; idx < O * (K / 2); idx += 256) {
        int o = idx / (K / 2), kk = idx - o * (K / 2);
        float2 w2 = ((const float2*)W)[o * (K / 2) + kk];
        wsh[o * P2 + kk] = __floats2half2_rn(w2.x, w2.y);
    }
    __syncthreads();
    int wave = (blockIdx.x * 256 + threadIdx.x) >> 6;
    if (wave >= Mtiles) return;
    int lane = threadIdx.x & 63;
    int lm = lane & 15, q = lane >> 4;
    long long m0 = (long long)wave * 16;
    constexpr int NT = (O + 15) / 16;
    f32x4 acc[NT];
    #pragma unroll
    for (int j = 0; j < NT; ++j) acc[j] = (f32x4){0.f, 0.f, 0.f, 0.f};
    const __half* wsp = (const __half*)wsh;
    #pragma unroll
    for (int k0 = 0; k0 < K; k0 += 32) {
        f16x8 a;
        if (FP32IN) {
            const float* xr = (const float*)in_ + (m0 + lm) * K + k0 + q * 8;
            float4 x0 = ((const float4*)xr)[0];
            float4 x1 = ((const float4*)xr)[1];
            a = (f16x8){(_Float16)x0.x, (_Float16)x0.y, (_Float16)x0.z, (_Float16)x0.w,
                        (_Float16)x1.x, (_Float16)x1.y, (_Float16)x1.z, (_Float16)x1.w};
        } else {
            const __half* xr = (const __half*)in_ + (m0 + lm) * K + k0 + q * 8;
            a = *(const f16x8*)xr;
        }
        #pragma unroll
        for (int j = 0; j < NT; ++j) {
            f16x8 b = *(const f16x8*)(wsp + (16 * j + lm) * (2 * P2) + k0 + q * 8);
            acc[j] = __builtin_amdgcn_mfma_f32_16x16x32_f16(a, b, acc[j], 0, 0, 0);
        }
    }
    #pragma unroll
    for (int r = 0; r < 4; ++r) {
        long long m = m0 + q * 4 + r;
        float sc = SCALE ? dinv[m] : 1.0f;
        #pragma unroll
        for (int j = 0; j < NT; ++j) {
            int col = 16 * j + lm;
            if (col < O) out[m * O + col] = __float2half(acc[j][r] * sc);
        }
    }
}

// ---------------- bias + log_softmax over 40 channels, one wave per node --------
__global__ void softmax40_k(const __half* __restrict__ in, const float* __restrict__ bias,
                            float* __restrict__ out, int N) {
    int gtid = blockIdx.x * blockDim.x + threadIdx.x;
    int node = gtid >> 6;
    int lane = gtid & 63;
    if (node >= N) return;
    float v = -INFINITY;
    if (lane < OUT_C) v = __half2float(in[(long long)node * OUT_C + lane]) + bias[lane];
    float m = v;
    #pragma unroll
    for (int off = 32; off >= 1; off >>= 1) m = fmaxf(m, __shfl_xor(m, off));
    float e = (lane < OUT_C) ? expf(v - m) : 0.0f;
    float s = e;
    #pragma unroll
    for (int off = 32; off >= 1; off >>= 1) s += __shfl_xor(s, off);
    float ls = logf(s);
    if (lane < OUT_C) out[(long long)node * OUT_C + lane] = (v - m) - ls;
}

// ---------------- launcher ----------------
static inline int cdiv(long long a, long long b) { return (int)((a + b - 1) / b); }
static inline size_t align256(size_t x) { return (x + 255) & ~(size_t)255; }

extern "C" void kernel_launch(void* const* d_in, const int* in_sizes, int n_in,
                              void* d_out, int out_size, void* d_ws, size_t ws_size,
                              hipStream_t stream) {
    const float* x  = (const float*)d_in[0];
    const void*  ei = d_in[1];
    const float* W0 = (const float*)d_in[2];
    const float* b0 = (const float*)d_in[3];
    const float* W4 = (const float*)d_in[4];
    const float* b4 = (const float*)d_in[5];
    float* out = (float*)d_out;

    const int N = N_NODES, E = N_EDGES;
    const int NB = cdiv(N, 256);
    char* ws = (char*)d_ws;
    int*    flag   = (int*)ws;     ws += 256;
    int*    deg    = (int*)ws;     ws += align256((size_t)N * 4);
    int*    rowptr = (int*)ws;     ws += align256((size_t)(N + 1) * 4);
    int*    cursor = (int*)ws;     ws += align256((size_t)N * 4);
    int*    part   = (int*)ws;     ws += align256(256 * 4);
    float*  dinv   = (float*)ws;   ws += align256((size_t)N * 4);
    int*    csrc   = (int*)ws;     ws += align256((size_t)E * 4);
    __half* bufA   = (__half*)ws;  ws += align256((size_t)N * HID_C * 2);
    __half* bufB   = (__half*)ws;  ws += align256((size_t)N * HID_C * 2);
    __half* bufC   = (__half*)ws;  ws += align256((size_t)N * HID_C * 2);

    const int T = 256;
    const int NPB = T / 64;          // nodes per block in prop16_k
    const int MT = N / 16;           // 3125 MFMA tiles (N divisible by 16)
    const int LB = cdiv(MT, 4);      // mfma_lin blocks (4 waves each)

    detect_i64_k<<<1, 1, 0, stream>>>((const unsigned int*)ei, flag);

    // ---- CSR build ----
    zero_int_k<<<cdiv(N, T), T, 0, stream>>>(deg, N);
    deg_hist_k<<<cdiv(E, T), T, 0, stream>>>(ei, flag, deg, E);
    scan_p1_k<<<NB, 256, 0, stream>>>(deg, part, N);
    scan_p2_k<<<1, 256, 0, stream>>>(part, NB, rowptr, N);
    scan_p3_k<<<NB, 256, 0, stream>>>(deg, part, rowptr, cursor, dinv, N);
    csr_fill_k<<<cdiv(E, T), T, 0, stream>>>(ei, flag, cursor, csrc, E);

    // ---- conv0 (SGConv, K=2): linear folded first; output G-space ----
    mfma_lin_k<HID_C, IN_C, true, true><<<LB, 256, 0, stream>>>(x, W0, dinv, bufA, MT);
    prop16_k<HID_C, 2, false, false, false><<<cdiv(N, NPB), T, 0, stream>>>(
        rowptr, csrc, dinv, bufA, nullptr, nullptr, bufB, N);
    prop16_k<HID_C, 2, false, false, true><<<cdiv(N, NPB), T, 0, stream>>>(
        rowptr, csrc, dinv, bufB, nullptr, b0, bufC, N);  // + dinv*b0 -> Gh0

    // ---- conv1..conv3: leaky(APPNP(h)) entirely in G-space, Gh0 = bufC ----
    for (int r = 0; r < 3; ++r) {
        prop16_k<HID_C, 2, true, false, false><<<cdiv(N, NPB), T, 0, stream>>>(
            rowptr, csrc, dinv, bufC, bufC, nullptr, bufB, N);
        // in-place bufC write safe: Gh0[node] read only by the wave writing it
        prop16_k<HID_C, 2, true, true, false><<<cdiv(N, NPB), T, 0, stream>>>(
            rowptr, csrc, dinv, bufB, bufC, nullptr, bufC, N);
    }

    // ---- conv4 (SGConv, K=2): G-space in -> G-space lin out (no scale) ----
    mfma_lin_k<OUT_C, HID_C, false, false><<<LB, 256, 0, stream>>>(bufC, W4, dinv, bufA, MT);
    prop16_k<OUT_C, 2, false, false, false><<<cdiv(N, NPB), T, 0, stream>>>(
        rowptr, csrc, dinv, bufA, nullptr, nullptr, bufB, N);
    prop16_k<OUT_C, 1, false, false, false><<<cdiv(N, NPB), T, 0, stream>>>(
        rowptr, csrc, dinv, bufB, nullptr, nullptr, bufA, N);  // h-space out

    // ---- + b4, log_softmax ----
    softmax40_k<<<cdiv((long long)N * 64, T), T, 0, stream>>>(bufA, b4, out, N);
}

// Round 6
// 454.722 us; speedup vs baseline: 4.8946x; 1.0960x over previous
//
#include <hip/hip_runtime.h>
#include <hip/hip_fp16.h>
#include <math.h>

#define N_NODES 50000
#define N_EDGES 800000
#define IN_C 96
#define HID_C 64
#define OUT_C 40
#define ALPHA 0.2f
#define NEG_SLOPE 0.01f

typedef _Float16 f16x8 __attribute__((ext_vector_type(8)));
typedef float f32x4 __attribute__((ext_vector_type(4)));

__device__ __forceinline__ int edge_at(const void* ei, int is64, long long pos) {
    return is64 ? (int)((const long long*)ei)[pos] : ((const int*)ei)[pos];
}

// ---------------- zero deg + edge dtype detect (fused) ----------------
__global__ void zero_detect_k(int* deg, int n, const unsigned int* ei, int* flag) {
    int i = blockIdx.x * blockDim.x + threadIdx.x;
    if (i < n) deg[i] = 0;
    if (i == 0) {
        int is64 = 1;
        for (int j = 1; j < 16; j += 2)
            if (ei[j] != 0u) is64 = 0;
        *flag = is64;
    }
}

__global__ void deg_hist_k(const void* ei, const int* flag, int* deg, int E) {
    int e = blockIdx.x * blockDim.x + threadIdx.x;
    if (e < E) {
        int d = edge_at(ei, *flag, (long long)E + e);
        atomicAdd(&deg[d], 1);
    }
}

// ---- parallel 3-phase exclusive scan over deg[n] ----
__global__ void scan_p1_k(const int* __restrict__ deg, int* __restrict__ part, int n) {
    __shared__ int sm[256];
    int t = threadIdx.x, i = blockIdx.x * 256 + t;
    int v = (i < n) ? deg[i] : 0;
    sm[t] = v;
    __syncthreads();
    for (int off = 1; off < 256; off <<= 1) {
        int u = (t >= off) ? sm[t - off] : 0;
        __syncthreads();
        sm[t] += u;
        __syncthreads();
    }
    if (t == 255) part[blockIdx.x] = sm[255];
}

__global__ void scan_p2_k(int* part, int nb, int* rowptr, int n) {
    __shared__ int sm[256];
    int t = threadIdx.x;
    int v = (t < nb) ? part[t] : 0;
    sm[t] = v;
    __syncthreads();
    for (int off = 1; off < 256; off <<= 1) {
        int u = (t >= off) ? sm[t - off] : 0;
        __syncthreads();
        sm[t] += u;
        __syncthreads();
    }
    if (t < nb) part[t] = sm[t] - v;  // exclusive
    if (t == 255) rowptr[n] = sm[255];
}

__global__ void scan_p3_k(const int* __restrict__ deg, const int* __restrict__ part,
                          int* __restrict__ rowptr, int* __restrict__ cursor,
                          float* __restrict__ dinv, int n) {
    __shared__ int sm[256];
    int t = threadIdx.x, i = blockIdx.x * 256 + t;
    int v = (i < n) ? deg[i] : 0;
    sm[t] = v;
    __syncthreads();
    for (int off = 1; off < 256; off <<= 1) {
        int u = (t >= off) ? sm[t - off] : 0;
        __syncthreads();
        sm[t] += u;
        __syncthreads();
    }
    if (i < n) {
        int excl = sm[t] - v + part[blockIdx.x];
        rowptr[i] = excl;
        cursor[i] = excl;
        dinv[i] = rsqrtf((float)v + 1.0f);  // +1 self loop
    }
}

// fill CSR, XCD-partitioned: blockIdx%8 owns dst range [p*N/8,(p+1)*N/8).
// With round-robin block->XCD dispatch, csrc lines of a range are written by
// ONE XCD -> one line writeback instead of cross-XCD ping-pong.
#define FILL_CHUNK 8192
__global__ void csr_fill_k(const void* ei, const int* flag,
                           int* __restrict__ cursor, int* __restrict__ csrc,
                           int E, int N) {
    int p = blockIdx.x & 7;
    int chunk = blockIdx.x >> 3;
    int lo = p * (N / 8), hi = lo + (N / 8);  // 50000/8 = 6250 exact
    int e0 = chunk * FILL_CHUNK;
    int e1 = e0 + FILL_CHUNK; if (e1 > E) e1 = E;
    int f = *flag;
    for (int e = e0 + threadIdx.x; e < e1; e += blockDim.x) {
        int d = edge_at(ei, f, (long long)E + e);
        if (d >= lo && d < hi) {
            int s = edge_at(ei, f, e);
            int pos = atomicAdd(&cursor[d], 1);
            csrc[pos] = s;
        }
    }
}

// ---------------- C=64 prop: quarter-wave gathers (16 lanes x 8B per row) ------
// G-space (G = dinv*h): S = sum G[src] + G[node]; v = dinv^2*S (+dinv*b)
// (+APPNP combine with Gh0) (+leaky). 4 rows per wave-instr, 4-deep unroll.
template <bool COMBINE, bool LEAKY, bool BIAS>
__global__ void prop64_k(const int* __restrict__ rowptr, const int* __restrict__ csrc,
                         const float* __restrict__ dinv,
                         const __half* __restrict__ in, const __half* __restrict__ h0,
                         const float* __restrict__ bias,
                         __half* __restrict__ out, int N) {
    int node = blockIdx.x * (blockDim.x >> 6) + (threadIdx.x >> 6);
    int lane = threadIdx.x & 63;
    int sub = lane >> 4;   // 0..3 quarter-waves walk interleaved edges
    int ci  = lane & 15;   // 16 lanes x 4ch = 64 channels
    if (node >= N) return;
    const float2* in4 = (const float2*)in;  // 8B = 4 halves (bit-carrier)
    f32x4 acc = {0.f, 0.f, 0.f, 0.f};
    if (sub == 0) {  // self-loop term G[node]
        float2 r = in4[node * 16 + ci];
        float2 a = __half22float2(*(const __half2*)&r.x);
        float2 b = __half22float2(*(const __half2*)&r.y);
        acc[0] = a.x; acc[1] = a.y; acc[2] = b.x; acc[3] = b.y;
    }
    int r0 = rowptr[node], r1 = rowptr[node + 1];
    int i = r0 + sub;
    for (; i + 12 < r1; i += 16) {
        int s0 = csrc[i], s1 = csrc[i + 4], s2 = csrc[i + 8], s3 = csrc[i + 12];
        float2 v0 = in4[s0 * 16 + ci];
        float2 v1 = in4[s1 * 16 + ci];
        float2 v2 = in4[s2 * 16 + ci];
        float2 v3 = in4[s3 * 16 + ci];
        float2 a0 = __half22float2(*(const __half2*)&v0.x), b0 = __half22float2(*(const __half2*)&v0.y);
        float2 a1 = __half22float2(*(const __half2*)&v1.x), b1 = __half22float2(*(const __half2*)&v1.y);
        float2 a2 = __half22float2(*(const __half2*)&v2.x), b2 = __half22float2(*(const __half2*)&v2.y);
        float2 a3 = __half22float2(*(const __half2*)&v3.x), b3 = __half22float2(*(const __half2*)&v3.y);
        acc[0] += (a0.x + a1.x) + (a2.x + a3.x);
        acc[1] += (a0.y + a1.y) + (a2.y + a3.y);
        acc[2] += (b0.x + b1.x) + (b2.x + b3.x);
        acc[3] += (b0.y + b1.y) + (b2.y + b3.y);
    }
    for (; i < r1; i += 4) {
        float2 v0 = in4[csrc[i] * 16 + ci];
        float2 a0 = __half22float2(*(const __half2*)&v0.x), b0 = __half22float2(*(const __half2*)&v0.y);
        acc[0] += a0.x; acc[1] += a0.y; acc[2] += b0.x; acc[3] += b0.y;
    }
    #pragma unroll
    for (int j = 0; j < 4; ++j) {
        acc[j] += __shfl_xor(acc[j], 16);
        acc[j] += __shfl_xor(acc[j], 32);
    }
    if (sub == 0) {
        float di = dinv[node];
        float sc = di * di;
        float4 v;
        v.x = sc * acc[0]; v.y = sc * acc[1]; v.z = sc * acc[2]; v.w = sc * acc[3];
        if (BIAS) {
            const float4 b = ((const float4*)bias)[ci];
            v.x += di * b.x; v.y += di * b.y; v.z += di * b.z; v.w += di * b.w;
        }
        if (COMBINE) {
            float2 r = ((const float2*)h0)[node * 16 + ci];
            float2 a = __half22float2(*(const __half2*)&r.x);
            float2 b = __half22float2(*(const __half2*)&r.y);
            v.x = (1.0f - ALPHA) * v.x + ALPHA * a.x;
            v.y = (1.0f - ALPHA) * v.y + ALPHA * a.y;
            v.z = (1.0f - ALPHA) * v.z + ALPHA * b.x;
            v.w = (1.0f - ALPHA) * v.w + ALPHA * b.y;
        }
        if (LEAKY) {
            v.x = v.x > 0.0f ? v.x : NEG_SLOPE * v.x;
            v.y = v.y > 0.0f ? v.y : NEG_SLOPE * v.y;
            v.z = v.z > 0.0f ? v.z : NEG_SLOPE * v.z;
            v.w = v.w > 0.0f ? v.w : NEG_SLOPE * v.w;
        }
        float2 o;
        *(__half2*)&o.x = __float22half2_rn(make_float2(v.x, v.y));
        *(__half2*)&o.y = __float22half2_rn(make_float2(v.z, v.w));
        ((float2*)out)[node * 16 + ci] = o;
    }
}

// ---------------- C=40 prop, half-wave scheme (used for conv4 first hop) -------
// G-space in -> G-space out (scale dinv^2).
__global__ void prop40_k(const int* __restrict__ rowptr, const int* __restrict__ csrc,
                         const float* __restrict__ dinv,
                         const __half* __restrict__ in, __half* __restrict__ out, int N) {
    constexpr int CP = OUT_C / 2;  // 20
    int node = blockIdx.x * (blockDim.x >> 6) + (threadIdx.x >> 6);
    int lane = threadIdx.x & 63;
    int sub = lane >> 5;
    int ci = lane & 31;
    if (node >= N) return;
    bool act = ci < CP;
    const __half2* in2 = (const __half2*)in;
    float2 acc = make_float2(0.0f, 0.0f);
    if (sub == 0 && act) {
        float2 v = __half22float2(in2[(long long)node * CP + ci]);
        acc.x = v.x; acc.y = v.y;
    }
    int r0 = rowptr[node], r1 = rowptr[node + 1];
    int i = r0 + sub;
    for (; i + 6 < r1; i += 8) {
        int s0 = csrc[i], s1 = csrc[i + 2], s2 = csrc[i + 4], s3 = csrc[i + 6];
        if (act) {
            float2 v0 = __half22float2(in2[(long long)s0 * CP + ci]);
            float2 v1 = __half22float2(in2[(long long)s1 * CP + ci]);
            float2 v2 = __half22float2(in2[(long long)s2 * CP + ci]);
            float2 v3 = __half22float2(in2[(long long)s3 * CP + ci]);
            acc.x += (v0.x + v1.x) + (v2.x + v3.x);
            acc.y += (v0.y + v1.y) + (v2.y + v3.y);
        }
    }
    for (; i < r1; i += 2) {
        int s0 = csrc[i];
        if (act) {
            float2 v0 = __half22float2(in2[(long long)s0 * CP + ci]);
            acc.x += v0.x; acc.y += v0.y;
        }
    }
    acc.x += __shfl_xor(acc.x, 32);
    acc.y += __shfl_xor(acc.y, 32);
    if (sub == 0 && act) {
        float di = dinv[node];
        float sc = di * di;
        ((__half2*)out)[(long long)node * CP + ci] =
            __float22half2_rn(make_float2(sc * acc.x, sc * acc.y));
    }
}

// ---------------- final C=40 prop + b4 + log_softmax fused, fp32 out -----------
// in is G-space; v = dinv*S + b4 (h-space); then log_softmax over the 40 cols.
__global__ void prop40_softmax_k(const int* __restrict__ rowptr, const int* __restrict__ csrc,
                                 const float* __restrict__ dinv,
                                 const __half* __restrict__ in, const float* __restrict__ bias,
                                 float* __restrict__ out, int N) {
    constexpr int CP = OUT_C / 2;  // 20
    int node = blockIdx.x * (blockDim.x >> 6) + (threadIdx.x >> 6);
    int lane = threadIdx.x & 63;
    int sub = lane >> 5;
    int ci = lane & 31;
    if (node >= N) return;
    bool act = ci < CP;
    const __half2* in2 = (const __half2*)in;
    float2 acc = make_float2(0.0f, 0.0f);
    if (sub == 0 && act) {
        float2 v = __half22float2(in2[(long long)node * CP + ci]);
        acc.x = v.x; acc.y = v.y;
    }
    int r0 = rowptr[node], r1 = rowptr[node + 1];
    int i = r0 + sub;
    for (; i + 6 < r1; i += 8) {
        int s0 = csrc[i], s1 = csrc[i + 2], s2 = csrc[i + 4], s3 = csrc[i + 6];
        if (act) {
            float2 v0 = __half22float2(in2[(long long)s0 * CP + ci]);
            float2 v1 = __half22float2(in2[(long long)s1 * CP + ci]);
            float2 v2 = __half22float2(in2[(long long)s2 * CP + ci]);
            float2 v3 = __half22float2(in2[(long long)s3 * CP + ci]);
            acc.x += (v0.x + v1.x) + (v2.x + v3.x);
            acc.y += (v0.y + v1.y) + (v2.y + v3.y);
        }
    }
    for (; i < r1; i += 2) {
        int s0 = csrc[i];
        if (act) {
            float2 v0 = __half22float2(in2[(long long)s0 * CP + ci]);
            acc.x += v0.x; acc.y += v0.y;
        }
    }
    acc.x += __shfl_xor(acc.x, 32);
    acc.y += __shfl_xor(acc.y, 32);
    // epilogue on sub0's 32 lanes (20 active); butterfly within 32-lane group
    if (sub == 0) {
        float di = dinv[node];
        float2 v = make_float2(-INFINITY, -INFINITY);
        if (act) {
            v.x = di * acc.x + bias[2 * ci];
            v.y = di * acc.y + bias[2 * ci + 1];
        }
        float m = fmaxf(v.x, v.y);
        #pragma unroll
        for (int off = 16; off >= 1; off >>= 1) m = fmaxf(m, __shfl_xor(m, off));
        float e = act ? (expf(v.x - m) + expf(v.y - m)) : 0.0f;
        #pragma unroll
        for (int off = 16; off >= 1; off >>= 1) e += __shfl_xor(e, off);
        float ls = m + logf(e);
        if (act)
            ((float2*)out)[(long long)node * CP + ci] = make_float2(v.x - ls, v.y - ls);
    }
}

// ---------------- MFMA dense linear: out[m,o] = sum_k in[m,k]*W[o,k] -----------
template <int O, int K, bool FP32IN, bool SCALE>
__global__ void __launch_bounds__(256) mfma_lin_k(const void* __restrict__ in_,
                                                  const float* __restrict__ W,
                                                  const float* __restrict__ dinv,
                                                  __half* __restrict__ out, int Mtiles) {
    constexpr int P2 = 52;  // half2 pitch (104 halves = 208 B rows, 16B-aligned)
    __shared__ __half2 wsh[O * P2];
    for (int idx = threadIdx.x; idx < O * (K / 2); idx += 256) {
        int o = idx / (K / 2), kk = idx - o * (K / 2);
        float2 w2 = ((const float2*)W)[o * (K / 2) + kk];
        wsh[o * P2 + kk] = __floats2half2_rn(w2.x, w2.y);
    }
    __syncthreads();
    int wave = (blockIdx.x * 256 + threadIdx.x) >> 6;
    if (wave >= Mtiles) return;
    int lane = threadIdx.x & 63;
    int lm = lane & 15, q = lane >> 4;
    long long m0 = (long long)wave * 16;
    constexpr int NT = (O + 15) / 16;
    f32x4 acc[NT];
    #pragma unroll
    for (int j = 0; j < NT; ++j) acc[j] = (f32x4){0.f, 0.f, 0.f, 0.f};
    const __half* wsp = (const __half*)wsh;
    #pragma unroll
    for (int k0 = 0; k0 < K; k0 += 32) {
        f16x8 a;
        if (FP32IN) {
            const float* xr = (const float*)in_ + (m0 + lm) * K + k0 + q * 8;
            float4 x0 = ((const float4*)xr)[0];
            float4 x1 = ((const float4*)xr)[1];
            a = (f16x8){(_Float16)x0.x, (_Float16)x0.y, (_Float16)x0.z, (_Float16)x0.w,
                        (_Float16)x1.x, (_Float16)x1.y, (_Float16)x1.z, (_Float16)x1.w};
        } else {
            const __half* xr = (const __half*)in_ + (m0 + lm) * K + k0 + q * 8;
            a = *(const f16x8*)xr;
        }
        #pragma unroll
        for (int j = 0; j < NT; ++j) {
            f16x8 b = *(const f16x8*)(wsp + (16 * j + lm) * (2 * P2) + k0 + q * 8);
            acc[j] = __builtin_amdgcn_mfma_f32_16x16x32_f16(a, b, acc[j], 0, 0, 0);
        }
    }
    #pragma unroll
    for (int r = 0; r < 4; ++r) {
        long long m = m0 + q * 4 + r;
        float sc = SCALE ? dinv[m] : 1.0f;
        #pragma unroll
        for (int j = 0; j < NT; ++j) {
            int col = 16 * j + lm;
            if (col < O) out[m * O + col] = __float2half(acc[j][r] * sc);
        }
    }
}

// ---------------- launcher ----------------
static inline int cdiv(long long a, long long b) { return (int)((a + b - 1) / b); }
static inline size_t align256(size_t x) { return (x + 255) & ~(size_t)255; }

extern "C" void kernel_launch(void* const* d_in, const int* in_sizes, int n_in,
                              void* d_out, int out_size, void* d_ws, size_t ws_size,
                              hipStream_t stream) {
    const float* x  = (const float*)d_in[0];
    const void*  ei = d_in[1];
    const float* W0 = (const float*)d_in[2];
    const float* b0 = (const float*)d_in[3];
    const float* W4 = (const float*)d_in[4];
    const float* b4 = (const float*)d_in[5];
    float* out = (float*)d_out;

    const int N = N_NODES, E = N_EDGES;
    const int NB = cdiv(N, 256);
    char* ws = (char*)d_ws;
    int*    flag   = (int*)ws;     ws += 256;
    int*    deg    = (int*)ws;     ws += align256((size_t)N * 4);
    int*    rowptr = (int*)ws;     ws += align256((size_t)(N + 1) * 4);
    int*    cursor = (int*)ws;     ws += align256((size_t)N * 4);
    int*    part   = (int*)ws;     ws += align256(256 * 4);
    float*  dinv   = (float*)ws;   ws += align256((size_t)N * 4);
    int*    csrc   = (int*)ws;     ws += align256((size_t)E * 4);
    __half* bufA   = (__half*)ws;  ws += align256((size_t)N * HID_C * 2);
    __half* bufB   = (__half*)ws;  ws += align256((size_t)N * HID_C * 2);
    __half* bufC   = (__half*)ws;  ws += align256((size_t)N * HID_C * 2);

    const int T = 256;
    const int NPB = T / 64;          // nodes (waves) per block in prop kernels
    const int MT = N / 16;           // 3125 MFMA tiles
    const int LB = cdiv(MT, 4);      // mfma_lin blocks (4 waves each)

    // ---- CSR build ----
    zero_detect_k<<<cdiv(N, T), T, 0, stream>>>(deg, N, (const unsigned int*)ei, flag);
    deg_hist_k<<<cdiv(E, T), T, 0, stream>>>(ei, flag, deg, E);
    scan_p1_k<<<NB, 256, 0, stream>>>(deg, part, N);
    scan_p2_k<<<1, 256, 0, stream>>>(part, NB, rowptr, N);
    scan_p3_k<<<NB, 256, 0, stream>>>(deg, part, rowptr, cursor, dinv, N);
    csr_fill_k<<<cdiv(E, FILL_CHUNK) * 8, T, 0, stream>>>(ei, flag, cursor, csrc, E, N);

    // ---- conv0 (SGConv, K=2): linear folded first; output G-space ----
    mfma_lin_k<HID_C, IN_C, true, true><<<LB, 256, 0, stream>>>(x, W0, dinv, bufA, MT);
    prop64_k<false, false, false><<<cdiv(N, NPB), T, 0, stream>>>(
        rowptr, csrc, dinv, bufA, nullptr, nullptr, bufB, N);
    prop64_k<false, false, true><<<cdiv(N, NPB), T, 0, stream>>>(
        rowptr, csrc, dinv, bufB, nullptr, b0, bufC, N);  // + dinv*b0 -> Gh0

    // ---- conv1..conv3: leaky(APPNP(h)) entirely in G-space, Gh0 = bufC ----
    for (int r = 0; r < 3; ++r) {
        prop64_k<true, false, false><<<cdiv(N, NPB), T, 0, stream>>>(
            rowptr, csrc, dinv, bufC, bufC, nullptr, bufB, N);
        // in-place bufC write safe: Gh0[node] read only by the wave writing it
        prop64_k<true, true, false><<<cdiv(N, NPB), T, 0, stream>>>(
            rowptr, csrc, dinv, bufB, bufC, nullptr, bufC, N);
    }

    // ---- conv4 (SGConv, K=2): G-space lin (no scale), then 2 hops at 40ch ----
    mfma_lin_k<OUT_C, HID_C, false, false><<<LB, 256, 0, stream>>>(bufC, W4, dinv, bufA, MT);
    prop40_k<<<cdiv(N, NPB), T, 0, stream>>>(rowptr, csrc, dinv, bufA, bufB, N);
    prop40_softmax_k<<<cdiv(N, NPB), T, 0, stream>>>(rowptr, csrc, dinv, bufB, b4, out, N);
}